// Round 5
// baseline (1091.543 us; speedup 1.0000x reference)
//
#include <hip/hip_runtime.h>
#include <hip/hip_fp16.h>
#include <cstdint>
#include <cstddef>

#define NN 50000
#define NE 800000
#define EPSV 1e-5f
#define NTILES (NE / 128)  // 6250
#define PGRID 1024         // 4 blocks/CU x 256 CUs

typedef _Float16 f16_t;
typedef f16_t f16x8 __attribute__((ext_vector_type(8)));
typedef f16_t f16x4 __attribute__((ext_vector_type(4)));
typedef f16_t f16x2 __attribute__((ext_vector_type(2)));
typedef float f32x4 __attribute__((ext_vector_type(4)));

__device__ __forceinline__ float fast_tanh(float x) {
  float e2 = __expf(2.f * x);
  return 1.f - 2.f / (e2 + 1.f);
}
__device__ __forceinline__ float fast_sigmoid(float x) {
  return 1.f / (1.f + __expf(-x));
}

// ---------------------------------------------------------------------------
// node projection: P_sw = f16(node_emb @ Wn^T + b1), stored SWIZZLED:
//   P_sw[node][w*64 + l16*4 + nt] = (node_emb @ Wn^T + b1)[node][16w + 64nt + l16]
// ---------------------------------------------------------------------------
__launch_bounds__(256, 4)
__global__ void node_proj(const float* __restrict__ A, const float* __restrict__ w1,
                          const float* __restrict__ b1, f16_t* __restrict__ P) {
  __shared__ f16_t Alds[128][136];
  const int tid = threadIdx.x;
  const int wave = tid >> 6;
  const int lane = tid & 63;
  const int quad = lane >> 4;
  const int l16 = lane & 15;

  int cols[4];
#pragma unroll
  for (int nt = 0; nt < 4; ++nt) cols[nt] = 16 * wave + 64 * nt + l16;

  f16x8 bfrag[4][4];  // B[k=8*quad+j][n=l16] == w1[n][k] (Wn half)
#pragma unroll
  for (int nt = 0; nt < 4; ++nt)
#pragma unroll
    for (int ks = 0; ks < 4; ++ks) {
      const float* src = w1 + (size_t)cols[nt] * 256 + ks * 32 + quad * 8;
#pragma unroll
      for (int j = 0; j < 8; ++j) bfrag[nt][ks][j] = (f16_t)src[j];
    }

  float c0[4];
#pragma unroll
  for (int nt = 0; nt < 4; ++nt) c0[nt] = b1[cols[nt]];

  const int row0 = blockIdx.x * 128;
  {
    const int r = tid >> 1, half = tid & 1;
    const int grow = row0 + r;
    f16_t* dst = &Alds[r][half * 64];
    if (grow < NN) {
      const float4* src = (const float4*)(A + (size_t)grow * 128 + half * 64);
#pragma unroll
      for (int c = 0; c < 8; ++c) {
        float4 v0 = src[2 * c], v1 = src[2 * c + 1];
        f16x8 pk = {(f16_t)v0.x, (f16_t)v0.y, (f16_t)v0.z, (f16_t)v0.w,
                    (f16_t)v1.x, (f16_t)v1.y, (f16_t)v1.z, (f16_t)v1.w};
        *(f16x8*)(dst + c * 8) = pk;
      }
    } else {
      f16x8 z = {0, 0, 0, 0, 0, 0, 0, 0};
#pragma unroll
      for (int c = 0; c < 8; ++c) *(f16x8*)(dst + c * 8) = z;
    }
  }
  __syncthreads();

#pragma unroll 1
  for (int m = 0; m < 8; ++m) {
    f16x8 afrag[4];
#pragma unroll
    for (int ks = 0; ks < 4; ++ks)
      afrag[ks] = *(const f16x8*)&Alds[m * 16 + l16][ks * 32 + quad * 8];
    f32x4 acc[4];
#pragma unroll
    for (int nt = 0; nt < 4; ++nt) acc[nt] = (f32x4){0.f, 0.f, 0.f, 0.f};
#pragma unroll
    for (int ks = 0; ks < 4; ++ks)
#pragma unroll
      for (int nt = 0; nt < 4; ++nt)
        acc[nt] = __builtin_amdgcn_mfma_f32_16x16x32_f16(
            afrag[ks], bfrag[nt][ks], acc[nt], 0, 0, 0);
    const int rbase = row0 + m * 16 + quad * 4;
#pragma unroll
    for (int reg = 0; reg < 4; ++reg) {
      int g = rbase + reg;
      if (g < NN) {
        f16x4 pk;
#pragma unroll
        for (int nt = 0; nt < 4; ++nt) pk[nt] = (f16_t)(acc[nt][reg] + c0[nt]);
        *(f16x4*)&P[(size_t)g * 256 + wave * 64 + l16 * 4] = pk;
      }
    }
  }
}

// ---------------------------------------------------------------------------
// edge passes (persistent blocks, work-stealing via atomic tile counter).
// MODE 1: column sum/sumsq of h = P_sw[idx] + edge @ We^T   -> stats[512]
// MODE 2: compute BN1 scale/shift from stats in-prologue; hn = h*s+t;
//         msg = sig(f)*tanh(c); packed-f16 atomic scatter into acc16.
// P-gathers software-pipelined one m-iter ahead (validated round 4:
// VALUBusy 34->18, HBM 20->46%).
// ---------------------------------------------------------------------------
template <int MODE>
__launch_bounds__(256, 4)
__global__ void edge_pass(const float* __restrict__ A, const float* __restrict__ w1,
                          const int* __restrict__ idx, const f16_t* __restrict__ P,
                          float* __restrict__ stats, const float* __restrict__ g1,
                          const float* __restrict__ be1, f16_t* __restrict__ acc16,
                          int* __restrict__ ctr) {
  __shared__ f16_t Alds[128][136];
  __shared__ int sIdx[128];
  __shared__ int s_tile;
  const int tid = threadIdx.x;
  const int wave = tid >> 6;
  const int lane = tid & 63;
  const int quad = lane >> 4;
  const int l16 = lane & 15;

  int cols[4];
#pragma unroll
  for (int nt = 0; nt < 4; ++nt) cols[nt] = 16 * wave + 64 * nt + l16;

  f16x8 bfrag[4][4];  // We half: w1[n][128 + k]
#pragma unroll
  for (int nt = 0; nt < 4; ++nt)
#pragma unroll
    for (int ks = 0; ks < 4; ++ks) {
      const float* src = w1 + (size_t)cols[nt] * 256 + 128 + ks * 32 + quad * 8;
#pragma unroll
      for (int j = 0; j < 8; ++j) bfrag[nt][ks][j] = (f16_t)src[j];
    }

  float c0[4], c1c[4];
  if (MODE == 2) {
    // fold finalize1 here: scale/shift from raw sums (all blocks redundantly)
#pragma unroll
    for (int nt = 0; nt < 4; ++nt) {
      const int c = cols[nt];
      float mean = stats[c] * (1.f / NE);
      float var = stats[256 + c] * (1.f / NE) - mean * mean;
      float s = g1[c] * rsqrtf(var + EPSV);
      c0[nt] = s;
      c1c[nt] = be1[c] - mean * s;
    }
  }
  float ssum[4] = {0.f, 0.f, 0.f, 0.f};
  float ssq[4] = {0.f, 0.f, 0.f, 0.f};

  for (;;) {
    if (tid == 0) s_tile = atomicAdd(ctr, 1);
    __syncthreads();
    const int t = s_tile;
    if (t >= NTILES) break;
    const int row0 = t * 128;

    if (tid < 128) sIdx[tid] = idx[row0 + tid];
    {
      const int r = tid >> 1, half = tid & 1;
      const float4* src = (const float4*)(A + (size_t)(row0 + r) * 128 + half * 64);
      f16_t* dst = &Alds[r][half * 64];
#pragma unroll
      for (int c = 0; c < 8; ++c) {
        float4 v0 = src[2 * c], v1 = src[2 * c + 1];
        f16x8 pk = {(f16_t)v0.x, (f16_t)v0.y, (f16_t)v0.z, (f16_t)v0.w,
                    (f16_t)v1.x, (f16_t)v1.y, (f16_t)v1.z, (f16_t)v1.w};
        *(f16x8*)(dst + c * 8) = pk;
      }
    }
    __syncthreads();

    // prime the P-gather pipeline for m=0
    int nodeC[4];
    f16x4 pvC[4];
#pragma unroll
    for (int reg = 0; reg < 4; ++reg) {
      nodeC[reg] = sIdx[quad * 4 + reg];
      pvC[reg] = *(const f16x4*)&P[(size_t)nodeC[reg] * 256 + wave * 64 + l16 * 4];
    }

#pragma unroll 1
    for (int m = 0; m < 8; ++m) {
      // prefetch NEXT m's P rows first (wrapped at m=7: harmless L1 reload)
      const int mm = (m + 1) & 7;
      int nodeN[4];
      f16x4 pvN[4];
#pragma unroll
      for (int reg = 0; reg < 4; ++reg) {
        nodeN[reg] = sIdx[mm * 16 + quad * 4 + reg];
        pvN[reg] = *(const f16x4*)&P[(size_t)nodeN[reg] * 256 + wave * 64 + l16 * 4];
      }

      f16x8 afrag[4];
#pragma unroll
      for (int ks = 0; ks < 4; ++ks)
        afrag[ks] = *(const f16x8*)&Alds[m * 16 + l16][ks * 32 + quad * 8];

      f32x4 acc[4];
#pragma unroll
      for (int nt = 0; nt < 4; ++nt) acc[nt] = (f32x4){0.f, 0.f, 0.f, 0.f};
      __builtin_amdgcn_s_setprio(1);
#pragma unroll
      for (int ks = 0; ks < 4; ++ks)
#pragma unroll
        for (int nt = 0; nt < 4; ++nt)
          acc[nt] = __builtin_amdgcn_mfma_f32_16x16x32_f16(
              afrag[ks], bfrag[nt][ks], acc[nt], 0, 0, 0);
      __builtin_amdgcn_s_setprio(0);

#pragma unroll
      for (int reg = 0; reg < 4; ++reg) {
        float h[4];
#pragma unroll
        for (int nt = 0; nt < 4; ++nt) h[nt] = acc[nt][reg] + (float)pvC[reg][nt];
        if (MODE == 2) {
          float hn[4];
#pragma unroll
          for (int nt = 0; nt < 4; ++nt) hn[nt] = h[nt] * c0[nt] + c1c[nt];
          // filter: nt0 (col 16w+l16), nt1 (16w+64+l16); cores nt2, nt3
          float msg0 = fast_sigmoid(hn[0]) * fast_tanh(hn[2]);
          float msg1 = fast_sigmoid(hn[1]) * fast_tanh(hn[3]);
          float o0 = __shfl_xor(msg0, 1);
          float o1 = __shfl_xor(msg1, 1);
          const bool ev = (l16 & 1) == 0;
          f16x2 val;
          val[0] = (f16_t)(ev ? msg0 : o1);
          val[1] = (f16_t)(ev ? o0 : msg1);
          const int colb = 16 * wave + (ev ? 0 : 64) + (l16 & ~1);
          __half2* addr = (__half2*)&acc16[(size_t)nodeC[reg] * 128 + colb];
          unsafeAtomicAdd(addr, *(__half2*)&val);
        } else {
#pragma unroll
          for (int nt = 0; nt < 4; ++nt) {
            ssum[nt] += h[nt];
            ssq[nt] += h[nt] * h[nt];
          }
        }
      }
      // rotate pipeline
#pragma unroll
      for (int reg = 0; reg < 4; ++reg) {
        nodeC[reg] = nodeN[reg];
        pvC[reg] = pvN[reg];
      }
    }
    __syncthreads();  // Alds/sIdx reuse + s_tile rewrite
  }

  if (MODE == 1) {
#pragma unroll
    for (int nt = 0; nt < 4; ++nt) {
      float s = ssum[nt], q = ssq[nt];
      s += __shfl_xor(s, 16); s += __shfl_xor(s, 32);
      q += __shfl_xor(q, 16); q += __shfl_xor(q, 32);
      if (quad == 0) {
        atomicAdd(&stats[cols[nt]], s);
        atomicAdd(&stats[256 + cols[nt]], q);
      }
    }
  }
}

__global__ void bn2_stats(const f16_t* __restrict__ acc16, float* __restrict__ stats) {
  const int tid = threadIdx.x;  // 256 ; tid = ph*64 + c2
  const int c2 = tid & 63;      // half2 column pair (cols 2c2, 2c2+1)
  const int ph = tid >> 6;
  float s0 = 0.f, s1 = 0.f, q0 = 0.f, q1 = 0.f;
  for (int row = blockIdx.x * 4 + ph; row < NN; row += gridDim.x * 4) {
    f16x2 v = *(const f16x2*)&acc16[(size_t)row * 128 + 2 * c2];
    float a = (float)v[0], b = (float)v[1];
    s0 += a; q0 += a * a;
    s1 += b; q1 += b * b;
  }
  __shared__ float red[256][4];
  red[tid][0] = s0; red[tid][1] = s1; red[tid][2] = q0; red[tid][3] = q1;
  __syncthreads();
  if (ph == 0) {
    float a0 = 0.f, a1 = 0.f, b0 = 0.f, b1 = 0.f;
#pragma unroll
    for (int p = 0; p < 4; ++p) {
      a0 += red[p * 64 + c2][0]; a1 += red[p * 64 + c2][1];
      b0 += red[p * 64 + c2][2]; b1 += red[p * 64 + c2][3];
    }
    atomicAdd(&stats[2 * c2], a0);
    atomicAdd(&stats[2 * c2 + 1], a1);
    atomicAdd(&stats[128 + 2 * c2], b0);
    atomicAdd(&stats[128 + 2 * c2 + 1], b1);
  }
}

// final: BN2 scale/shift computed inline from raw sums (finalize2 folded in)
__global__ void final_kernel(const float* __restrict__ node_emb,
                             const float* __restrict__ bn2sums,
                             const float* __restrict__ g2, const float* __restrict__ be2,
                             const f16_t* __restrict__ acc16, float* __restrict__ out) {
  int i = blockIdx.x * blockDim.x + threadIdx.x;  // one float4 each
  if (i >= NN * 32) return;
  int c4 = i & 31;
  int row = i >> 5;
  float4 sm = ((const float4*)bn2sums)[c4];
  float4 sq = ((const float4*)(bn2sums + 128))[c4];
  float4 g = ((const float4*)g2)[c4];
  float4 b = ((const float4*)be2)[c4];
  float4 s4, h4;
  {
    float mean, var;
    mean = sm.x * (1.f / NN); var = sq.x * (1.f / NN) - mean * mean;
    s4.x = g.x * rsqrtf(var + EPSV); h4.x = b.x - mean * s4.x;
    mean = sm.y * (1.f / NN); var = sq.y * (1.f / NN) - mean * mean;
    s4.y = g.y * rsqrtf(var + EPSV); h4.y = b.y - mean * s4.y;
    mean = sm.z * (1.f / NN); var = sq.z * (1.f / NN) - mean * mean;
    s4.z = g.z * rsqrtf(var + EPSV); h4.z = b.z - mean * s4.z;
    mean = sm.w * (1.f / NN); var = sq.w * (1.f / NN) - mean * mean;
    s4.w = g.w * rsqrtf(var + EPSV); h4.w = b.w - mean * s4.w;
  }
  float4 ne = ((const float4*)node_emb)[i];
  f16x4 cv = *(const f16x4*)&acc16[(size_t)row * 128 + c4 * 4];
  float4 r;
  r.x = fast_tanh(ne.x + (float)cv[0] * s4.x + h4.x);
  r.y = fast_tanh(ne.y + (float)cv[1] * s4.y + h4.y);
  r.z = fast_tanh(ne.z + (float)cv[2] * s4.z + h4.z);
  r.w = fast_tanh(ne.w + (float)cv[3] * s4.w + h4.w);
  ((float4*)out)[i] = r;
}

extern "C" void kernel_launch(void* const* d_in, const int* in_sizes, int n_in,
                              void* d_out, int out_size, void* d_ws, size_t ws_size,
                              hipStream_t stream) {
  (void)in_sizes; (void)n_in; (void)out_size; (void)ws_size;
  const float* node_emb = (const float*)d_in[0];
  const float* edge_emb = (const float*)d_in[1];
  const int* idx = (const int*)d_in[2];
  const float* w1 = (const float*)d_in[3];
  const float* b1 = (const float*)d_in[4];
  const float* g1 = (const float*)d_in[5];
  const float* be1 = (const float*)d_in[6];
  const float* g2 = (const float*)d_in[7];
  const float* be2 = (const float*)d_in[8];
  float* out = (float*)d_out;

  // ws layout (floats): [0,512) bn1 sum+sumsq | [512,768) bn2 sum+sumsq |
  // [768] ctr1 | [769] ctr2
  // byte 8192+: P swizzled f16 (25.6 MB); f16 node accumulator (12.8 MB)
  float* wsf = (float*)d_ws;
  float* bn1sums = wsf;
  float* bn2sums = wsf + 512;
  int* ctr1 = (int*)(wsf + 768);
  int* ctr2 = (int*)(wsf + 769);
  char* base = (char*)d_ws + 8192;
  f16_t* P = (f16_t*)base;
  f16_t* acc16 = (f16_t*)(base + (size_t)NN * 512);

  hipMemsetAsync(wsf, 0, 1024 * sizeof(float), stream);
  hipMemsetAsync(acc16, 0, (size_t)NN * 256, stream);

  node_proj<<<(NN + 127) / 128, 256, 0, stream>>>(node_emb, w1, b1, P);
  edge_pass<1><<<PGRID, 256, 0, stream>>>(edge_emb, w1, idx, P, bn1sums, g1, be1,
                                          nullptr, ctr1);
  edge_pass<2><<<PGRID, 256, 0, stream>>>(edge_emb, w1, idx, P, bn1sums, g1, be1,
                                          acc16, ctr2);
  bn2_stats<<<128, 256, 0, stream>>>(acc16, bn2sums);
  final_kernel<<<(NN * 32 + 255) / 256, 256, 0, stream>>>(node_emb, bn2sums, g2,
                                                          be2, acc16, out);
}

// Round 6
// 900.201 us; speedup vs baseline: 1.2126x; 1.2126x over previous
//
#include <hip/hip_runtime.h>
#include <hip/hip_fp16.h>
#include <cstdint>
#include <cstddef>

#define NN 50000
#define NE 800000
#define EPSV 1e-5f
#define NTILES (NE / 128)  // 6250
#define EGRID 768          // 3 blocks/CU x 256 CUs (512 threads each)

typedef _Float16 f16_t;
typedef f16_t f16x8 __attribute__((ext_vector_type(8)));
typedef f16_t f16x4 __attribute__((ext_vector_type(4)));
typedef f16_t f16x2 __attribute__((ext_vector_type(2)));
typedef float f32x4 __attribute__((ext_vector_type(4)));

__device__ __forceinline__ float fast_tanh(float x) {
  float e2 = __expf(2.f * x);
  return 1.f - 2.f / (e2 + 1.f);
}
__device__ __forceinline__ float fast_sigmoid(float x) {
  return 1.f / (1.f + __expf(-x));
}

// ---------------------------------------------------------------------------
// node projection. P stored PAIR-SWIZZLED for the 8-wave edge kernel:
//   P[node][w*32 + l16*2 + n] = (node_emb @ Wn^T + b1)[node][16w + 128n + l16]
// (w in 0..7, n in 0..1). Verified correct in round 2.
// ---------------------------------------------------------------------------
__launch_bounds__(256, 4)
__global__ void node_proj(const float* __restrict__ A, const float* __restrict__ w1,
                          const float* __restrict__ b1, f16_t* __restrict__ P) {
  __shared__ f16_t Alds[128][136];
  const int tid = threadIdx.x;
  const int wave = tid >> 6;
  const int lane = tid & 63;
  const int quad = lane >> 4;
  const int l16 = lane & 15;

  int cols[4];
#pragma unroll
  for (int nt = 0; nt < 4; ++nt) cols[nt] = 16 * wave + 64 * nt + l16;

  f16x8 bfrag[4][4];  // B[k=8*quad+j][n=l16] == w1[n][k] (Wn half)
#pragma unroll
  for (int nt = 0; nt < 4; ++nt)
#pragma unroll
    for (int ks = 0; ks < 4; ++ks) {
      const float* src = w1 + (size_t)cols[nt] * 256 + ks * 32 + quad * 8;
#pragma unroll
      for (int j = 0; j < 8; ++j) bfrag[nt][ks][j] = (f16_t)src[j];
    }

  float c0[4];
#pragma unroll
  for (int nt = 0; nt < 4; ++nt) c0[nt] = b1[cols[nt]];

  const int row0 = blockIdx.x * 128;
  {
    const int r = tid >> 1, half = tid & 1;
    const int grow = row0 + r;
    f16_t* dst = &Alds[r][half * 64];
    if (grow < NN) {
      const float4* src = (const float4*)(A + (size_t)grow * 128 + half * 64);
#pragma unroll
      for (int c = 0; c < 8; ++c) {
        float4 v0 = src[2 * c], v1 = src[2 * c + 1];
        f16x8 pk = {(f16_t)v0.x, (f16_t)v0.y, (f16_t)v0.z, (f16_t)v0.w,
                    (f16_t)v1.x, (f16_t)v1.y, (f16_t)v1.z, (f16_t)v1.w};
        *(f16x8*)(dst + c * 8) = pk;
      }
    } else {
      f16x8 z = {0, 0, 0, 0, 0, 0, 0, 0};
#pragma unroll
      for (int c = 0; c < 8; ++c) *(f16x8*)(dst + c * 8) = z;
    }
  }
  __syncthreads();

#pragma unroll 1
  for (int m = 0; m < 8; ++m) {
    f16x8 afrag[4];
#pragma unroll
    for (int ks = 0; ks < 4; ++ks)
      afrag[ks] = *(const f16x8*)&Alds[m * 16 + l16][ks * 32 + quad * 8];
    f32x4 acc[4];
#pragma unroll
    for (int nt = 0; nt < 4; ++nt) acc[nt] = (f32x4){0.f, 0.f, 0.f, 0.f};
#pragma unroll
    for (int ks = 0; ks < 4; ++ks)
#pragma unroll
      for (int nt = 0; nt < 4; ++nt)
        acc[nt] = __builtin_amdgcn_mfma_f32_16x16x32_f16(
            afrag[ks], bfrag[nt][ks], acc[nt], 0, 0, 0);
    const int rbase = row0 + m * 16 + quad * 4;
#pragma unroll
    for (int reg = 0; reg < 4; ++reg) {
      int g = rbase + reg;
      if (g < NN) {
        // cols: nt0=16w+l16 (w=wave,n=0), nt2=+128 (n=1) -> slot wave*32+2*l16
        //       nt1=16(w+4)+l16 (n=0), nt3=+128 (n=1)    -> slot (wave+4)*32+2*l16
        f16x2 pA, pB;
        pA[0] = (f16_t)(acc[0][reg] + c0[0]);
        pA[1] = (f16_t)(acc[2][reg] + c0[2]);
        pB[0] = (f16_t)(acc[1][reg] + c0[1]);
        pB[1] = (f16_t)(acc[3][reg] + c0[3]);
        *(f16x2*)&P[(size_t)g * 256 + wave * 32 + l16 * 2] = pA;
        *(f16x2*)&P[(size_t)g * 256 + (wave + 4) * 32 + l16 * 2] = pB;
      }
    }
  }
}

// ---------------------------------------------------------------------------
// edge passes: 8 waves x nt=2 (cols 16w + 128n + l16), 512-thread blocks,
// 3 blocks/CU (24 waves/CU vs old 16) — same dataflow as the proven R1
// kernel, halved per-wave registers. Work-stealing tile loop.
// MODE 1: stats only.  MODE 2: apply + scatter (fallback).  MODE 3: stats +
// h-store into Hs (pair layout, same as P).
// ---------------------------------------------------------------------------
template <int MODE>
__launch_bounds__(512, 6)
__global__ void edge_pass(const float* __restrict__ A, const float* __restrict__ w1,
                          const int* __restrict__ idx, const f16_t* __restrict__ P,
                          float* __restrict__ stats, const float* __restrict__ st,
                          f16_t* __restrict__ outp, int* __restrict__ ctr) {
  __shared__ f16_t Alds[128][136];
  __shared__ int sIdx[128];
  __shared__ int s_tile;
  const int tid = threadIdx.x;
  const int w = tid >> 6;      // 0..7
  const int lane = tid & 63;
  const int quad = lane >> 4;
  const int l16 = lane & 15;

  int cols[2];
#pragma unroll
  for (int n = 0; n < 2; ++n) cols[n] = 16 * w + 128 * n + l16;

  f16x8 bfrag[2][4];  // We half: w1[col][128 + ks*32 + quad*8 + j]
#pragma unroll
  for (int n = 0; n < 2; ++n)
#pragma unroll
    for (int ks = 0; ks < 4; ++ks) {
      const float* src = w1 + (size_t)cols[n] * 256 + 128 + ks * 32 + quad * 8;
#pragma unroll
      for (int j = 0; j < 8; ++j) bfrag[n][ks][j] = (f16_t)src[j];
    }

  float c0[2], c1c[2];
  if (MODE == 2) {
#pragma unroll
    for (int n = 0; n < 2; ++n) {
      c0[n] = st[cols[n]];
      c1c[n] = st[256 + cols[n]];
    }
  }
  float ssum[2] = {0.f, 0.f};
  float ssq[2] = {0.f, 0.f};

  for (;;) {
    if (tid == 0) s_tile = atomicAdd(ctr, 1);
    __syncthreads();
    const int t = s_tile;
    if (t >= NTILES) break;
    const int row0 = t * 128;

    if (tid < 128) sIdx[tid] = idx[row0 + tid];
    {
      const int r = tid >> 2, q4 = tid & 3;  // 128 rows x 4 quarters
      const float4* src = (const float4*)(A + (size_t)(row0 + r) * 128 + q4 * 32);
      f16_t* dst = &Alds[r][q4 * 32];
#pragma unroll
      for (int c = 0; c < 4; ++c) {
        float4 v0 = src[2 * c], v1 = src[2 * c + 1];
        f16x8 pk = {(f16_t)v0.x, (f16_t)v0.y, (f16_t)v0.z, (f16_t)v0.w,
                    (f16_t)v1.x, (f16_t)v1.y, (f16_t)v1.z, (f16_t)v1.w};
        *(f16x8*)(dst + c * 8) = pk;
      }
    }
    __syncthreads();

#pragma unroll 1
    for (int m = 0; m < 8; ++m) {
      // P gathers first (longest latency), one f16x2 per reg
      int node[4];
      f16x2 pv[4];
#pragma unroll
      for (int reg = 0; reg < 4; ++reg) {
        node[reg] = sIdx[m * 16 + quad * 4 + reg];
        pv[reg] = *(const f16x2*)&P[(size_t)node[reg] * 256 + w * 32 + l16 * 2];
      }

      f16x8 afrag[4];
#pragma unroll
      for (int ks = 0; ks < 4; ++ks)
        afrag[ks] = *(const f16x8*)&Alds[m * 16 + l16][ks * 32 + quad * 8];

      f32x4 acc[2];
      acc[0] = (f32x4){0.f, 0.f, 0.f, 0.f};
      acc[1] = (f32x4){0.f, 0.f, 0.f, 0.f};
#pragma unroll
      for (int ks = 0; ks < 4; ++ks) {
        acc[0] = __builtin_amdgcn_mfma_f32_16x16x32_f16(afrag[ks], bfrag[0][ks],
                                                        acc[0], 0, 0, 0);
        acc[1] = __builtin_amdgcn_mfma_f32_16x16x32_f16(afrag[ks], bfrag[1][ks],
                                                        acc[1], 0, 0, 0);
      }

#pragma unroll
      for (int reg = 0; reg < 4; ++reg) {
        const float h0 = acc[0][reg] + (float)pv[reg][0];  // col 16w+l16 (filter)
        const float h1 = acc[1][reg] + (float)pv[reg][1];  // col +128    (core)
        if (MODE == 2) {
          const float hn0 = h0 * c0[0] + c1c[0];
          const float hn1 = h1 * c0[1] + c1c[1];
          const float msg = fast_sigmoid(hn0) * fast_tanh(hn1);  // col 16w+l16
          const float o = __shfl_xor(msg, 1);
          if ((l16 & 1) == 0) {
            f16x2 val;
            val[0] = (f16_t)msg;
            val[1] = (f16_t)o;
            __half2* addr =
                (__half2*)&outp[(size_t)node[reg] * 128 + 16 * w + (l16 & ~1)];
            unsafeAtomicAdd(addr, *(__half2*)&val);
          }
        } else {
          ssum[0] += h0; ssq[0] += h0 * h0;
          ssum[1] += h1; ssq[1] += h1 * h1;
          if (MODE == 3) {
            f16x2 hp = {(f16_t)h0, (f16_t)h1};
            const int edge = row0 + m * 16 + quad * 4 + reg;
            *(f16x2*)&outp[(size_t)edge * 256 + w * 32 + l16 * 2] = hp;
          }
        }
      }
    }
    __syncthreads();  // Alds/sIdx reuse + s_tile rewrite
  }

  if (MODE != 2) {
#pragma unroll
    for (int n = 0; n < 2; ++n) {
      float s = ssum[n], q = ssq[n];
      s += __shfl_xor(s, 16); s += __shfl_xor(s, 32);
      q += __shfl_xor(q, 16); q += __shfl_xor(q, 32);
      if (quad == 0) {
        atomicAdd(&stats[cols[n]], s);
        atomicAdd(&stats[256 + cols[n]], q);
      }
    }
  }
}

__global__ void finalize1(const float* __restrict__ stats, const float* __restrict__ g1,
                          const float* __restrict__ be1, float* __restrict__ st,
                          float* __restrict__ st_sw) {
  int j = threadIdx.x;  // 256
  float mean = stats[j] * (1.f / NE);
  float var = stats[256 + j] * (1.f / NE) - mean * mean;
  float s = g1[j] * rsqrtf(var + EPSV);
  float t = be1[j] - mean * s;
  st[j] = s;
  st[256 + j] = t;
  // pair-swizzled copy: col j = 16w + 128n + l16 -> pos w*32 + l16*2 + n
  int wq = (j >> 4) & 7, n = j >> 7, lj = j & 15;
  int pos = wq * 32 + lj * 2 + n;
  st_sw[pos] = s;
  st_sw[256 + pos] = t;
}

// ---------------------------------------------------------------------------
// streaming BN-apply + gated activation + packed-f16 atomic scatter.
// Pair layout puts (filter c, core c+128) adjacent: lane-local gating,
// two half2 atomics 128 B apart (identical geometry to the proven R1 apply).
// ---------------------------------------------------------------------------
__launch_bounds__(256, 8)
__global__ void edge_apply(const f16_t* __restrict__ hsw, const int* __restrict__ idx,
                           const float* __restrict__ stw, f16_t* __restrict__ acc16) {
  const int i = blockIdx.x * 256 + threadIdx.x;  // NE*32 threads exactly
  const int e = i >> 5;
  const int k2 = i & 31;
  const int node = idx[e];
  const int w = k2 >> 3, lp = k2 & 7;  // cols c..c+1 and c+64..c+65, c=16w+2lp
  const f16x4 ha = *(const f16x4*)&hsw[(size_t)e * 256 + w * 32 + lp * 4];
  const f16x4 hb = *(const f16x4*)&hsw[(size_t)e * 256 + (w + 4) * 32 + lp * 4];
  const float4 sA = *(const float4*)&stw[w * 32 + lp * 4];
  const float4 sB = *(const float4*)&stw[(w + 4) * 32 + lp * 4];
  const float4 tA = *(const float4*)&stw[256 + w * 32 + lp * 4];
  const float4 tB = *(const float4*)&stw[256 + (w + 4) * 32 + lp * 4];
  f16x2 va, vb;
  va[0] = (f16_t)(fast_sigmoid((float)ha[0] * sA.x + tA.x) *
                  fast_tanh((float)ha[1] * sA.y + tA.y));
  va[1] = (f16_t)(fast_sigmoid((float)ha[2] * sA.z + tA.z) *
                  fast_tanh((float)ha[3] * sA.w + tA.w));
  vb[0] = (f16_t)(fast_sigmoid((float)hb[0] * sB.x + tB.x) *
                  fast_tanh((float)hb[1] * sB.y + tB.y));
  vb[1] = (f16_t)(fast_sigmoid((float)hb[2] * sB.z + tB.z) *
                  fast_tanh((float)hb[3] * sB.w + tB.w));
  const int cA = 16 * w + 2 * lp;
  f16_t* rowp = acc16 + (size_t)node * 128;
  unsafeAtomicAdd((__half2*)(rowp + cA), *(__half2*)&va);
  unsafeAtomicAdd((__half2*)(rowp + 64 + cA), *(__half2*)&vb);
}

__global__ void bn2_stats(const f16_t* __restrict__ acc16, float* __restrict__ stats) {
  const int tid = threadIdx.x;  // 256 ; tid = ph*64 + c2
  const int c2 = tid & 63;
  const int ph = tid >> 6;
  float s0 = 0.f, s1 = 0.f, q0 = 0.f, q1 = 0.f;
  for (int row = blockIdx.x * 4 + ph; row < NN; row += gridDim.x * 4) {
    f16x2 v = *(const f16x2*)&acc16[(size_t)row * 128 + 2 * c2];
    float a = (float)v[0], b = (float)v[1];
    s0 += a; q0 += a * a;
    s1 += b; q1 += b * b;
  }
  __shared__ float red[256][4];
  red[tid][0] = s0; red[tid][1] = s1; red[tid][2] = q0; red[tid][3] = q1;
  __syncthreads();
  if (ph == 0) {
    float a0 = 0.f, a1 = 0.f, b0 = 0.f, b1 = 0.f;
#pragma unroll
    for (int p = 0; p < 4; ++p) {
      a0 += red[p * 64 + c2][0]; a1 += red[p * 64 + c2][1];
      b0 += red[p * 64 + c2][2]; b1 += red[p * 64 + c2][3];
    }
    atomicAdd(&stats[2 * c2], a0);
    atomicAdd(&stats[2 * c2 + 1], a1);
    atomicAdd(&stats[128 + 2 * c2], b0);
    atomicAdd(&stats[128 + 2 * c2 + 1], b1);
  }
}

// final: BN2 scale/shift computed inline from raw sums (verified round 5)
__global__ void final_kernel(const float* __restrict__ node_emb,
                             const float* __restrict__ bn2sums,
                             const float* __restrict__ g2, const float* __restrict__ be2,
                             const f16_t* __restrict__ acc16, float* __restrict__ out) {
  int i = blockIdx.x * blockDim.x + threadIdx.x;  // one float4 each
  if (i >= NN * 32) return;
  int c4 = i & 31;
  int row = i >> 5;
  float4 sm = ((const float4*)bn2sums)[c4];
  float4 sq = ((const float4*)(bn2sums + 128))[c4];
  float4 g = ((const float4*)g2)[c4];
  float4 b = ((const float4*)be2)[c4];
  float4 s4, h4;
  {
    float mean, var;
    mean = sm.x * (1.f / NN); var = sq.x * (1.f / NN) - mean * mean;
    s4.x = g.x * rsqrtf(var + EPSV); h4.x = b.x - mean * s4.x;
    mean = sm.y * (1.f / NN); var = sq.y * (1.f / NN) - mean * mean;
    s4.y = g.y * rsqrtf(var + EPSV); h4.y = b.y - mean * s4.y;
    mean = sm.z * (1.f / NN); var = sq.z * (1.f / NN) - mean * mean;
    s4.z = g.z * rsqrtf(var + EPSV); h4.z = b.z - mean * s4.z;
    mean = sm.w * (1.f / NN); var = sq.w * (1.f / NN) - mean * mean;
    s4.w = g.w * rsqrtf(var + EPSV); h4.w = b.w - mean * s4.w;
  }
  float4 ne = ((const float4*)node_emb)[i];
  f16x4 cv = *(const f16x4*)&acc16[(size_t)row * 128 + c4 * 4];
  float4 r;
  r.x = fast_tanh(ne.x + (float)cv[0] * s4.x + h4.x);
  r.y = fast_tanh(ne.y + (float)cv[1] * s4.y + h4.y);
  r.z = fast_tanh(ne.z + (float)cv[2] * s4.z + h4.z);
  r.w = fast_tanh(ne.w + (float)cv[3] * s4.w + h4.w);
  ((float4*)out)[i] = r;
}

extern "C" void kernel_launch(void* const* d_in, const int* in_sizes, int n_in,
                              void* d_out, int out_size, void* d_ws, size_t ws_size,
                              hipStream_t stream) {
  (void)in_sizes; (void)n_in; (void)out_size;
  const float* node_emb = (const float*)d_in[0];
  const float* edge_emb = (const float*)d_in[1];
  const int* idx = (const int*)d_in[2];
  const float* w1 = (const float*)d_in[3];
  const float* b1 = (const float*)d_in[4];
  const float* g1 = (const float*)d_in[5];
  const float* be1 = (const float*)d_in[6];
  const float* g2 = (const float*)d_in[7];
  const float* be2 = (const float*)d_in[8];
  float* out = (float*)d_out;

  // ws layout (floats): [0,512) bn1 sum+sumsq | [512,1024) bn1 scale/shift |
  // [1024,1280) bn2 sum+sumsq | [1536,1538) ctrs | [2048,2560) scale/shift SWZ
  // byte 16384+: P pair-swizzled f16 (25.6 MB); f16 node accumulator (12.8 MB);
  //              h pair-swizzled f16 (409.6 MB)
  float* wsf = (float*)d_ws;
  float* bn1sums = wsf;
  float* st = wsf + 512;
  float* bn2sums = wsf + 1024;
  int* ctr1 = (int*)(wsf + 1536);
  int* ctr2 = (int*)(wsf + 1537);
  float* st_sw = wsf + 2048;
  char* base = (char*)d_ws + 16384;
  f16_t* P = (f16_t*)base;
  f16_t* acc16 = (f16_t*)(base + (size_t)NN * 512);
  f16_t* hsw = (f16_t*)(base + (size_t)NN * 512 + (size_t)NN * 256);
  const size_t need_h = 16384 + (size_t)NN * 512 + (size_t)NN * 256 + (size_t)NE * 512;

  hipMemsetAsync(wsf, 0, 2560 * sizeof(float), stream);
  hipMemsetAsync(acc16, 0, (size_t)NN * 256, stream);

  node_proj<<<(NN + 127) / 128, 256, 0, stream>>>(node_emb, w1, b1, P);
  if (ws_size >= need_h) {
    // h-store pass + streaming scatter apply (R1 structure, 8-wave geometry)
    edge_pass<3><<<EGRID, 512, 0, stream>>>(edge_emb, w1, idx, P, bn1sums, nullptr,
                                            hsw, ctr1);
    finalize1<<<1, 256, 0, stream>>>(bn1sums, g1, be1, st, st_sw);
    edge_apply<<<NE * 32 / 256, 256, 0, stream>>>(hsw, idx, st_sw, acc16);
  } else {
    // fallback: two full edge passes
    edge_pass<1><<<EGRID, 512, 0, stream>>>(edge_emb, w1, idx, P, bn1sums, nullptr,
                                            nullptr, ctr1);
    finalize1<<<1, 256, 0, stream>>>(bn1sums, g1, be1, st, st_sw);
    edge_pass<2><<<EGRID, 512, 0, stream>>>(edge_emb, w1, idx, P, bn1sums, st,
                                            acc16, ctr2);
  }
  bn2_stats<<<256, 256, 0, stream>>>(acc16, bn2sums);
  final_kernel<<<(NN * 32 + 255) / 256, 256, 0, stream>>>(node_emb, bn2sums, g2,
                                                          be2, acc16, out);
}